// Round 2
// baseline (64.897 us; speedup 1.0000x reference)
//
#include <hip/hip_runtime.h>

#define NQ 16

// c*v0 - i*s*v1   (RX butterfly contribution)
__device__ __forceinline__ float2 rxmix(float2 v0, float2 v1, float c, float s) {
    return make_float2(c * v0.x + s * v1.y, c * v0.y - s * v1.x);
}

// One block per sample, 512 threads (8 waves), 2 blocks/CU -> 4 waves/SIMD.
//
// state = C2 R2 C1 R1 |0>;  RX angles merge (R1 absorbs layer-0), ring CNOTs are
// basis permutations, C2 is absorbed into the measurement (nested Z-string masks).
// C1 chi is rank-4 across the hi(0..7)/lo(8..15) cut:
//   X_{2a+t}(h) = A_t(h) [h&1==a],  Y_{2a+b}(l) = B_a(l) [l&1==b].
// R2 wires wb+0..wb+6 act on element bits 7..1 and commute with the bit-0
// projector, so each array splits into independent even/odd (bit-0) halves:
// Phase A: wave (arr, e0) builds + rotates its 128-element half (2 elems/lane,
//   element e = (k<<7)|(lane<<1)|e0; wire wb+0 = register butterfly over k,
//   wires wb+1..wb+6 = shfl_xor masks 32..1).
// Phase B: thread (e = tid&255, side = tid>>8) forms 16 pair-products for its
//   side only, 64-pt WHT over lane bits, prefix-mask lanes dump partials.
// Phase C: 4-wave combine into G[side][m][pp]; Phase D: out[i].
extern "C" __global__ __launch_bounds__(512, 4)
void qsim_kernel(const float* __restrict__ z,
                 const float* __restrict__ params,
                 const float* __restrict__ ew,
                 float* __restrict__ out)
{
    const int b    = blockIdx.x;
    const int tid  = threadIdx.x;
    const int lane = tid & 63;
    const int wv   = tid >> 6;

    __shared__ float2 V4[4][2][128];        // [arr][e0][f = (k<<6)|lane]
    __shared__ float  PART[4][7][2][17];    // [w2][prefix][side][product(+pad)]
    __shared__ float2 G[2][9][10];

    // ---- Phase A identity: wave -> (array, bit0-half) ----
    const int  arr = wv >> 1;               // 0:A0 1:A1 2:B0 3:B1
    const int  e0w = wv & 1;
    const bool hiw = (arr < 2);
    const int  par = arr & 1;
    const int  p1  = hiw ? par : 0;
    const int  wb  = hiw ? 0 : 8;

    // Per-wave trig, no shared tables, no prologue barrier:
    // lane j<8: embed+layer0 angle of wire wb+j; lane 8..15: layer-1 of wire wb+(lane-8).
    float myA = 0.f;
    if (lane < 8) {
        const int q = wb + lane;
        myA = 0.5f * (z[b * NQ + q] + params[q] + ew[q]);
    } else if (lane < 16) {
        const int q = wb + (lane - 8);      // lane 15 -> wire wb+7 (used in Phase B)
        myA = 0.5f * ew[NQ + q];
    }
    float myS, myC;
    sincosf(myA, &myS, &myC);

    const float c1_0 = __shfl(myC, 0), s1_0 = __shfl(myS, 0);
    const float c1_1 = __shfl(myC, 1), s1_1 = __shfl(myS, 1);
    const float c1_2 = __shfl(myC, 2), s1_2 = __shfl(myS, 2);
    const float c1_3 = __shfl(myC, 3), s1_3 = __shfl(myS, 3);
    const float c1_4 = __shfl(myC, 4), s1_4 = __shfl(myS, 4);
    const float c1_5 = __shfl(myC, 5), s1_5 = __shfl(myS, 5);
    const float c1_6 = __shfl(myC, 6), s1_6 = __shfl(myS, 6);
    const float c1_7 = __shfl(myC, 7), s1_7 = __shfl(myS, 7);
    const float cw0  = __shfl(myC, 8),  sw0 = __shfl(myS, 8);
    const float cw1  = __shfl(myC, 9),  sw1 = __shfl(myS, 9);
    const float cw2  = __shfl(myC, 10), sw2 = __shfl(myS, 10);
    const float cw3  = __shfl(myC, 11), sw3 = __shfl(myS, 11);
    const float cw4  = __shfl(myC, 12), sw4 = __shfl(myS, 12);
    const float cw5  = __shfl(myC, 13), sw5 = __shfl(myS, 13);
    const float cw6  = __shfl(myC, 14), sw6 = __shfl(myS, 14);

    // ---- Step 2: build the 2 elements e = (k<<7)|(lane<<1)|e0w ----
    // eb factors: wire wb+0: k^par; wb+1: lane5^k^p1; wb+2..wb+6: gray(lane) bits
    // 4..0; wb+7: lane0^e0w.
    const int gl  = (lane ^ (lane >> 1)) & 31;
    const int l5  = (lane >> 5) & 1;
    const int eb7 = (lane & 1) ^ e0w;

    float t0 = ((gl >> 4) & 1) ? s1_2 : c1_2;
    float t1 = ((gl >> 3) & 1) ? s1_3 : c1_3;
    float t2 = ((gl >> 2) & 1) ? s1_4 : c1_4;
    float t3 = ((gl >> 1) & 1) ? s1_5 : c1_5;
    float t4 = ((gl >> 0) & 1) ? s1_6 : c1_6;
    float t5 = eb7 ? s1_7 : c1_7;
    const float laneMag = ((t0 * t1) * (t2 * t3)) * (t4 * t5);
    const int   laneKK  = __popc(gl) + eb7;

    const float f00 = par ? s1_0 : c1_0;    // k=0, wire wb+0
    const float f01 = par ? c1_0 : s1_0;    // k=1
    const int   e1k0 = l5 ^ p1;
    const float f10 = e1k0 ? s1_1 : c1_1;   // k=0, wire wb+1
    const float f11 = e1k0 ? c1_1 : s1_1;   // k=1

    float mag0 = laneMag * (f00 * f10);
    float mag1 = laneMag * (f01 * f11);
    int kk0 = laneKK + par + e1k0;
    int kk1 = laneKK + (1 ^ par) + (1 ^ e1k0);
    float sg0 = (kk0 & 2) ? -mag0 : mag0;
    float sg1 = (kk1 & 2) ? -mag1 : mag1;
    float2 v0r = (kk0 & 1) ? make_float2(0.f, -sg0) : make_float2(sg0, 0.f);
    float2 v1r = (kk1 & 1) ? make_float2(0.f, -sg1) : make_float2(sg1, 0.f);

    // ---- Step 3: layer-1 rotations on wires wb+0..wb+6 (e bits 7..1) ----
    {   // wire wb+0 <-> e bit7 = k: register butterfly
        float2 n0 = rxmix(v0r, v1r, cw0, sw0);
        float2 n1 = rxmix(v1r, v0r, cw0, sw0);
        v0r = n0; v1r = n1;
    }
#define ROT(cc, ss, mm) do {                                              \
        float px = __shfl_xor(v0r.x, mm), py = __shfl_xor(v0r.y, mm);     \
        v0r = make_float2((cc) * v0r.x + (ss) * py,                       \
                          (cc) * v0r.y - (ss) * px);                      \
        px = __shfl_xor(v1r.x, mm); py = __shfl_xor(v1r.y, mm);           \
        v1r = make_float2((cc) * v1r.x + (ss) * py,                       \
                          (cc) * v1r.y - (ss) * px);                      \
    } while (0)
    ROT(cw1, sw1, 32);   // wire wb+1 <-> lane bit5
    ROT(cw2, sw2, 16);
    ROT(cw3, sw3, 8);
    ROT(cw4, sw4, 4);
    ROT(cw5, sw5, 2);
    ROT(cw6, sw6, 1);    // wire wb+6 <-> lane bit0
#undef ROT

    V4[arr][e0w][lane]      = v0r;   // f = lane        (k=0)
    V4[arr][e0w][64 + lane] = v1r;   // f = 64 + lane   (k=1)
    __syncthreads();

    // ---- Phase B: thread -> (element e = tid&255, side ph = tid>>8) ----
    const int e  = tid & 255;
    const int ph = tid >> 8;         // 0: x-side (A0,A1,c7/s7)  1: y-side (B0,B1,c15/s15)
    const int f  = e >> 1;
    const int e0 = e & 1;
    const int w2 = wv & 3;           // = e bits 7..6

    // wire wb+7 layer-1 trig computed by lane 15 in Phase A of this same wave:
    // waves 0-3 (hi) hold cw[7], waves 4-7 (lo) hold cw[15] -- exactly this side's.
    const float cS = __shfl(myC, 15);
    const float sS = __shfl(myS, 15);

    const int baseArr = ph ? 2 : 0;
    const float2 r0a = V4[baseArr][0][f];       // first array,  e0=0 element
    const float2 r0b = V4[baseArr][1][f];       // first array,  e0=1 element
    const float2 r1a = V4[baseArr + 1][0][f];   // second array, e0=0 element
    const float2 r1b = V4[baseArr + 1][1][f];   // second array, e0=1 element

    float2 p0, p1v, p2, p3;
    if (ph == 0) {   // x[2a+t]: a=0 -> cS*alpha_t ; a=1 -> -i sS * beta_t
        if (e0 == 0) {
            p0  = make_float2(cS * r0a.x, cS * r0a.y);
            p1v = make_float2(cS * r1a.x, cS * r1a.y);
            p2  = make_float2(sS * r0b.y, -sS * r0b.x);
            p3  = make_float2(sS * r1b.y, -sS * r1b.x);
        } else {
            p0  = make_float2(sS * r0a.y, -sS * r0a.x);
            p1v = make_float2(sS * r1a.y, -sS * r1a.x);
            p2  = make_float2(cS * r0b.x, cS * r0b.y);
            p3  = make_float2(cS * r1b.x, cS * r1b.y);
        }
    } else {         // y[2a+b]: b=0 -> cS*gamma_a ; b=1 -> -i sS * delta_a
        if (e0 == 0) {
            p0  = make_float2(cS * r0a.x, cS * r0a.y);
            p2  = make_float2(cS * r1a.x, cS * r1a.y);
            p1v = make_float2(sS * r0b.y, -sS * r0b.x);
            p3  = make_float2(sS * r1b.y, -sS * r1b.x);
        } else {
            p0  = make_float2(sS * r0a.y, -sS * r0a.x);
            p2  = make_float2(sS * r1a.y, -sS * r1a.x);
            p1v = make_float2(cS * r0b.x, cS * r0b.y);
            p3  = make_float2(cS * r1b.x, cS * r1b.y);
        }
    }

    float wr[16];
    wr[0]  = p0.x * p0.x + p0.y * p0.y;
    wr[1]  = p1v.x * p1v.x + p1v.y * p1v.y;
    wr[2]  = p2.x * p2.x + p2.y * p2.y;
    wr[3]  = p3.x * p3.x + p3.y * p3.y;
    wr[4]  = p0.x * p1v.x + p0.y * p1v.y;
    wr[5]  = p0.y * p1v.x - p0.x * p1v.y;
    wr[6]  = p0.x * p2.x + p0.y * p2.y;
    wr[7]  = p0.y * p2.x - p0.x * p2.y;
    wr[8]  = p0.x * p3.x + p0.y * p3.y;
    wr[9]  = p0.y * p3.x - p0.x * p3.y;
    wr[10] = p1v.x * p2.x + p1v.y * p2.y;
    wr[11] = p1v.y * p2.x - p1v.x * p2.y;
    wr[12] = p1v.x * p3.x + p1v.y * p3.y;
    wr[13] = p1v.y * p3.x - p1v.x * p3.y;
    wr[14] = p2.x * p3.x + p2.y * p3.y;
    wr[15] = p2.y * p3.x - p2.x * p3.y;

    // ---- 64-point WHT over lane bits (= e bits 5..0) ----
#pragma unroll
    for (int lev = 0; lev < 6; ++lev) {
        int m = 1 << lev;
        float s = (lane & m) ? -1.f : 1.f;
#pragma unroll
        for (int a = 0; a < 16; ++a) {
            float wp = __shfl_xor(wr[a], m);
            wr[a] = fmaf(s, wr[a], wp);
        }
    }
    {   // prefix-mask lanes (lane == top-down prefix of bits 5..0) dump partials
        const int p = __popc(lane);
        if (lane == ((63 >> (6 - p)) << (6 - p))) {
#pragma unroll
            for (int a = 0; a < 16; ++a) PART[w2][p][ph][a] = wr[a];
        }
    }
    __syncthreads();

    // ---- Phase C: combine e bits 7..6 into G[side][m][pp] ----
    if (tid < 180) {
        int side = tid / 90, rest = tid - side * 90;
        int pp = rest / 9, m = rest - pp * 9;
        int M;
        if (side == 0) M = (m < 8) ? (((1 << (m + 1)) - 1) << (7 - m)) : 0x7F;
        else           M = (m == 0) ? 0 : (((1 << m) - 1) << (8 - m));
        int low = M & 63, hi2 = M >> 6;
        int li2 = __popc(low);                       // low is always a prefix mask
        int rs   = (int)((0x3E2CA18640ULL >> (4 * pp)) & 0xF);
        bool diag = (0x291 >> pp) & 1;               // pp in {0,4,7,9}
        float gr = 0.f, gi = 0.f;
#pragma unroll
        for (int w = 0; w < 4; ++w) {
            float s = (__popc(hi2 & w) & 1) ? -1.f : 1.f;
            gr = fmaf(s, PART[w][li2][side][rs], gr);
            if (!diag) gi = fmaf(s, PART[w][li2][side][rs + 1], gi);
        }
        G[side][m][pp] = make_float2(gr, gi);
    }
    __syncthreads();

    // ---- Phase D: out[i] = sum_pp w_pp * Re(Gh * Gl) ----
    if (tid < NQ) {
        const int i = tid;
        int hm, lm;
        if (i == 0)      { hm = 8; lm = 8; }     // Z-string {1..15}
        else if (i <= 7) { hm = i; lm = 0; }     // {0..i}
        else             { hm = 7; lm = i - 7; } // {0..i}
        float r = 0.f;
#pragma unroll
        for (int pp = 0; pp < 10; ++pp) {
            float2 gh = G[0][hm][pp];
            float2 gl = G[1][lm][pp];
            float re = gh.x * gl.x - gh.y * gl.y;
            float wgt = ((0x291 >> pp) & 1) ? 1.f : 2.f;
            r = fmaf(wgt, re, r);
        }
        out[b * NQ + i] = r;
    }
}

extern "C" void kernel_launch(void* const* d_in, const int* in_sizes, int n_in,
                              void* d_out, int out_size, void* d_ws, size_t ws_size,
                              hipStream_t stream) {
    const float* z      = (const float*)d_in[0];
    const float* params = (const float*)d_in[1];
    const float* ew     = (const float*)d_in[2];
    float* out          = (float*)d_out;
    const int B = in_sizes[0] / NQ;
    qsim_kernel<<<B, 512, 0, stream>>>(z, params, ew, out);
}

// Round 3
// 62.931 us; speedup vs baseline: 1.0312x; 1.0312x over previous
//
#include <hip/hip_runtime.h>

#define NQ 16

// c*v0 - i*s*v1   (RX butterfly contribution)
__device__ __forceinline__ float2 rxmix(float2 v0, float2 v1, float c, float s) {
    return make_float2(c * v0.x + s * v1.y, c * v0.y - s * v1.x);
}

// One block per sample, 256 threads (4 waves).
//
// state = C2 R2 C1 R1 |0>;  RX angles merge (R1 absorbs layer-0), ring CNOTs are
// basis permutations, C2 is absorbed into the measurement (nested Z-string masks).
// C1 chi is rank-4 across the hi(0..7)/lo(8..15) cut:
//   X_{2a+t}(h) = A_t(h) [h&1==a],  Y_{2a+b}(l) = B_a(l) [l&1==b].
// R2 = (wires0..6)(wire7) x (wires8..14)(wire15); wires 0..6/8..14 act on bits 7..1
// and commute with the bit-0 projector, so we rotate only 4 arrays (A0,A1,B0,B1)
// and apply wires 7/15 as scalar 2x2 factors in the product phase.
// Gram sums G[side][m][pp] = sum_e sgn_m(e) u_p(e) conj(u_q(e)) are computed via a
// 64-point Walsh-Hadamard over lane bits (shfl_xor butterflies) + 4-wave combine.
extern "C" __global__ __launch_bounds__(256)
void qsim_kernel(const float* __restrict__ z,
                 const float* __restrict__ params,
                 const float* __restrict__ ew,
                 float* __restrict__ out)
{
    const int b    = blockIdx.x;
    const int tid  = threadIdx.x;
    const int lane = tid & 63;
    const int wv   = tid >> 6;        // wave id = array id (0:A0 1:A1 2:B0 3:B1)

    __shared__ float c1[NQ], s1[NQ], cw[NQ], sw[NQ];
    __shared__ __align__(16) float2 V4[4][258];     // rotated arrays, padded rows
    __shared__ __align__(16) float  PART[4][7][33]; // [wave][low-mask idx][array], padded
    __shared__ float2 G[2][9][10];

    if (tid < 32) {
        const int q = tid & 15;
        if (tid < 16) {
            // embed + layer0 merged
            float phi = 0.5f * (z[b * NQ + q] + params[q] + ew[q]);
            float ss, cc;
            sincosf(phi, &ss, &cc);
            c1[q] = cc; s1[q] = ss;
        } else {
            float w = 0.5f * ew[NQ + q];  // layer1 RX
            float ss, cc;
            sincosf(w, &ss, &cc);
            cw[q] = cc; sw[q] = ss;
        }
    }
    __syncthreads();

    const bool hiw = (wv < 2);
    const int  par = wv & 1;          // t (hi) or a (lo) parameter of my array
    const int  wb  = hiw ? 0 : 8;

    // ---- Step 2: build my array's 4 elements e = (k<<6)|lane ----
    // Factorization: with e = (k<<6)|lane, a=k>>1, b=k&1, b5=lane>>5:
    //   wire wb+0: eb = a ^ par
    //   wire wb+1: eb = (a^b) ^ (hiw ? par : 0)
    //   wire wb+2: eb = b ^ b5
    //   wire wb+3+j (j=0..4): eb = graycode(lane) bit (4-j)   [lane-only]
    const int b5 = (lane >> 5) & 1;
    const int gl = (lane ^ (lane >> 1)) & 31;
    float t0 = ((gl >> 4) & 1) ? s1[wb + 3] : c1[wb + 3];
    float t1 = ((gl >> 3) & 1) ? s1[wb + 4] : c1[wb + 4];
    float t2 = ((gl >> 2) & 1) ? s1[wb + 5] : c1[wb + 5];
    float t3 = ((gl >> 1) & 1) ? s1[wb + 6] : c1[wb + 6];
    float t4 = ( gl       & 1) ? s1[wb + 7] : c1[wb + 7];
    const float laneMag = (t0 * t1) * (t2 * t3) * t4;  // tree: depth 3
    const int   laneKK  = __popc(gl);

    // shared 2-entry tables for the k-dependent wires
    const int p1 = hiw ? par : 0;
    float w0v0 = par ? s1[wb]     : c1[wb];       // a=0
    float w0v1 = par ? c1[wb]     : s1[wb];       // a=1
    float w1v0 = p1  ? s1[wb + 1] : c1[wb + 1];   // a^b=0
    float w1v1 = p1  ? c1[wb + 1] : s1[wb + 1];   // a^b=1
    float m2v0 = b5  ? s1[wb + 2] : c1[wb + 2];   // b=0
    float m2v1 = b5  ? c1[wb + 2] : s1[wb + 2];   // b=1

    float2 v[4];
#pragma unroll
    for (int k = 0; k < 4; ++k) {
        const int a = k >> 1, bb = k & 1, ab = a ^ bb;
        float wa = a  ? w0v1 : w0v0;
        float wc = ab ? w1v1 : w1v0;
        float wd = bb ? m2v1 : m2v0;
        float mag = laneMag * ((wa * wc) * wd);
        int kk = laneKK + (a ^ par) + (ab ^ p1) + (bb ^ b5);
        float sg = (kk & 2) ? -mag : mag;
        v[k] = (kk & 1) ? make_float2(0.f, -sg) : make_float2(sg, 0.f);
    }

    // ---- Step 3: rotate through 7 wires (bits 7..1). Wave-uniform angles. ----
    {   // bit 7 (wire wb+0): pairs (0,2),(1,3)
        float c = cw[wb + 0], s = sw[wb + 0];
        float2 n0 = rxmix(v[0], v[2], c, s), n2 = rxmix(v[2], v[0], c, s);
        float2 n1 = rxmix(v[1], v[3], c, s), n3 = rxmix(v[3], v[1], c, s);
        v[0] = n0; v[1] = n1; v[2] = n2; v[3] = n3;
    }
    {   // bit 6 (wire wb+1): pairs (0,1),(2,3)
        float c = cw[wb + 1], s = sw[wb + 1];
        float2 n0 = rxmix(v[0], v[1], c, s), n1 = rxmix(v[1], v[0], c, s);
        float2 n2 = rxmix(v[2], v[3], c, s), n3 = rxmix(v[3], v[2], c, s);
        v[0] = n0; v[1] = n1; v[2] = n2; v[3] = n3;
    }
#pragma unroll
    for (int bbit = 5; bbit >= 1; --bbit) {   // wires wb+2..wb+6
        float c = cw[wb + 7 - bbit], s = sw[wb + 7 - bbit];
        int m = 1 << bbit;
#pragma unroll
        for (int k = 0; k < 4; ++k) {
            float px = __shfl_xor(v[k].x, m);
            float py = __shfl_xor(v[k].y, m);
            v[k] = make_float2(c * v[k].x + s * py, c * v[k].y - s * px);
        }
    }
#pragma unroll
    for (int k = 0; k < 4; ++k) V4[wv][(k << 6) | lane] = v[k];
    __syncthreads();

    // ---- Step 4a: per-element sector values + pair products ----
    const int e0 = tid & 1, j2 = tid & ~1;
    float4 rA0 = *(const float4*)&V4[0][j2];   // (alpha0, beta0)
    float4 rA1 = *(const float4*)&V4[1][j2];   // (alpha1, beta1)
    float4 rB0 = *(const float4*)&V4[2][j2];   // (gamma0, delta0)
    float4 rB1 = *(const float4*)&V4[3][j2];   // (gamma1, delta1)
    float c7 = cw[7], s7 = sw[7], c15 = cw[15], s15 = sw[15];

    float2 x[4], yv[4];
    {
        float2 a0 = make_float2(rA0.x, rA0.y), b0 = make_float2(rA0.z, rA0.w);
        float2 a1 = make_float2(rA1.x, rA1.y), b1 = make_float2(rA1.z, rA1.w);
        if (e0 == 0) {  // x[2a+t]: a=0 -> c7*alpha_t ; a=1 -> -i s7 * beta_t
            x[0] = make_float2(c7 * a0.x, c7 * a0.y);
            x[1] = make_float2(c7 * a1.x, c7 * a1.y);
            x[2] = make_float2(s7 * b0.y, -s7 * b0.x);
            x[3] = make_float2(s7 * b1.y, -s7 * b1.x);
        } else {
            x[0] = make_float2(s7 * a0.y, -s7 * a0.x);
            x[1] = make_float2(s7 * a1.y, -s7 * a1.x);
            x[2] = make_float2(c7 * b0.x, c7 * b0.y);
            x[3] = make_float2(c7 * b1.x, c7 * b1.y);
        }
        float2 g0 = make_float2(rB0.x, rB0.y), d0 = make_float2(rB0.z, rB0.w);
        float2 g1 = make_float2(rB1.x, rB1.y), d1 = make_float2(rB1.z, rB1.w);
        if (e0 == 0) {  // y[2a+b]: b=0 -> c15*gamma_a ; b=1 -> -i s15 * delta_a
            yv[0] = make_float2(c15 * g0.x, c15 * g0.y);
            yv[2] = make_float2(c15 * g1.x, c15 * g1.y);
            yv[1] = make_float2(s15 * d0.y, -s15 * d0.x);
            yv[3] = make_float2(s15 * d1.y, -s15 * d1.x);
        } else {
            yv[0] = make_float2(s15 * g0.y, -s15 * g0.x);
            yv[2] = make_float2(s15 * g1.y, -s15 * g1.x);
            yv[1] = make_float2(c15 * d0.x, c15 * d0.y);
            yv[3] = make_float2(c15 * d1.x, c15 * d1.y);
        }
    }

    float wr[32];
    {
        float2 *p = x;
#pragma unroll
        for (int side = 0; side < 2; ++side, p = yv) {
            int o = side * 16;
            wr[o + 0] = p[0].x * p[0].x + p[0].y * p[0].y;
            wr[o + 1] = p[1].x * p[1].x + p[1].y * p[1].y;
            wr[o + 2] = p[2].x * p[2].x + p[2].y * p[2].y;
            wr[o + 3] = p[3].x * p[3].x + p[3].y * p[3].y;
            wr[o + 4]  = p[0].x * p[1].x + p[0].y * p[1].y;
            wr[o + 5]  = p[0].y * p[1].x - p[0].x * p[1].y;
            wr[o + 6]  = p[0].x * p[2].x + p[0].y * p[2].y;
            wr[o + 7]  = p[0].y * p[2].x - p[0].x * p[2].y;
            wr[o + 8]  = p[0].x * p[3].x + p[0].y * p[3].y;
            wr[o + 9]  = p[0].y * p[3].x - p[0].x * p[3].y;
            wr[o + 10] = p[1].x * p[2].x + p[1].y * p[2].y;
            wr[o + 11] = p[1].y * p[2].x - p[1].x * p[2].y;
            wr[o + 12] = p[1].x * p[3].x + p[1].y * p[3].y;
            wr[o + 13] = p[1].y * p[3].x - p[1].x * p[3].y;
            wr[o + 14] = p[2].x * p[3].x + p[2].y * p[3].y;
            wr[o + 15] = p[2].y * p[3].x - p[2].x * p[3].y;
        }
    }

    // ---- Step 4b: 64-point WHT over lane bits: lane L ends with signed sum
    //      sum_l (-1)^popc(L&l) wr(l) for every array ----
#pragma unroll
    for (int lev = 0; lev < 6; ++lev) {
        int m = 1 << lev;
        float s = (lane & m) ? -1.f : 1.f;
#pragma unroll
        for (int a = 0; a < 32; ++a) {
            float wp = __shfl_xor(wr[a], m);
            wr[a] = fmaf(s, wr[a], wp);
        }
    }
    {   // needed low-6 sign patterns: top-down prefix masks of bits 5..0.
        // lane is a prefix mask iff lane == (63 >> (6-p)) << (6-p), p = popc(lane);
        // its pattern index is then simply p.
        const int p = __popc(lane);
        if (lane == ((63 >> (6 - p)) << (6 - p))) {
#pragma unroll
            for (int a = 0; a < 32; ++a) PART[wv][p][a] = wr[a];
        }
    }
    __syncthreads();

    // ---- Step 4c: combine waves (bits 6,7) into G[side][m][pp] ----
    if (tid < 180) {
        int side = tid / 90, rest = tid - side * 90;
        int pp = rest / 9, m = rest - pp * 9;
        int M;
        if (side == 0) M = (m < 8) ? (((1 << (m + 1)) - 1) << (7 - m)) : 0x7F;
        else           M = (m == 0) ? 0 : (((1 << m) - 1) << (8 - m));
        int low = M & 63, hi2 = M >> 6;
        int li2 = __popc(low);                       // low is always a prefix mask
        int rs   = (int)((0x3E2CA18640ULL >> (4 * pp)) & 0xF);
        bool diag = (0x291 >> pp) & 1;               // pp in {0,4,7,9}
        float gr = 0.f, gi = 0.f;
#pragma unroll
        for (int w2 = 0; w2 < 4; ++w2) {
            float s = (__popc(hi2 & w2) & 1) ? -1.f : 1.f;
            gr = fmaf(s, PART[w2][li2][side * 16 + rs], gr);
            if (!diag) gi = fmaf(s, PART[w2][li2][side * 16 + rs + 1], gi);
        }
        G[side][m][pp] = make_float2(gr, gi);
    }
    __syncthreads();

    // ---- Step 5: out[i] = sum_pp w_pp * Re(Gh * Gl) ----
    if (tid < NQ) {
        const int i = tid;
        int hm, lm;
        if (i == 0)      { hm = 8; lm = 8; }     // Z-string {1..15}
        else if (i <= 7) { hm = i; lm = 0; }     // {0..i}
        else             { hm = 7; lm = i - 7; } // {0..i}
        float r = 0.f;
#pragma unroll
        for (int pp = 0; pp < 10; ++pp) {
            float2 gh = G[0][hm][pp];
            float2 gl = G[1][lm][pp];
            float re = gh.x * gl.x - gh.y * gl.y;
            float wgt = ((0x291 >> pp) & 1) ? 1.f : 2.f;
            r = fmaf(wgt, re, r);
        }
        out[b * NQ + i] = r;
    }
}

extern "C" void kernel_launch(void* const* d_in, const int* in_sizes, int n_in,
                              void* d_out, int out_size, void* d_ws, size_t ws_size,
                              hipStream_t stream) {
    const float* z      = (const float*)d_in[0];
    const float* params = (const float*)d_in[1];
    const float* ew     = (const float*)d_in[2];
    float* out          = (float*)d_out;
    const int B = in_sizes[0] / NQ;
    qsim_kernel<<<B, 256, 0, stream>>>(z, params, ew, out);
}